// Round 4
// baseline (447.935 us; speedup 1.0000x reference)
//
#include <hip/hip_runtime.h>

// Lukasiewicz t-norm feature expansion.
//   out[:, 0:16]    = x
//   out[:, 16:136]  = max(x[a]+x[b] - 1, 0)          (a,b)   lex combos of 16
//   out[:, 136:696] = max((x[a]+x[b]) + x[c] - 2, 0) (a,b,c) lex combos of 16
//
// R6: register-compute + per-wave LDS transpose. Evidence: NT vs plain and
// aligned vs split store variants all leave the kernel at ~137-162 us vs the
// 60 us write roofline (harness fill: 6.4 TB/s on the same buffer). The only
// remaining difference from the fill is CU-side work on the store dependency
// chain (12 scatter ds_read + table load + ~55 VALU per quad). This version
// removes ALL of it: each wave owns 64 rows, x[16] lives in registers with
// compile-time indices (template unroll -> no scratch), outputs are pure reg
// VALU, and an 8KB per-wave LDS slab transposes lane<->row to lane<->address
// so every store instruction covers 8 full 128B chunks. No table loads, no
// barriers (same-wave DS ops are issue-ordered; each read's data feeds a
// store before the next group's writes issue).
// FP order matches jnp.sum exactly: ((xa+xb)+xc)-2, (xa+xb)-1 -> absmax 0.
// Assumes nrows % 256 == 0 (harness: 131072).

#define NCOLS 696
#define NC4   174          // quads per row
#define NG    22           // 21 groups of 8 quads + tail group of 6

typedef float v4f __attribute__((ext_vector_type(4)));

struct Tabs { signed char a[NCOLS], b[NCOLS], c[NCOLS], t[NCOLS]; };
constexpr Tabs make_tabs() {
    Tabs T{};
    int k = 0;
    for (int a = 0; a < 16; ++a) {
        T.a[k] = (signed char)a; T.b[k] = 0; T.c[k] = 0; T.t[k] = 0; ++k;
    }
    for (int a = 0; a < 16; ++a)
        for (int b = a + 1; b < 16; ++b) {
            T.a[k] = (signed char)a; T.b[k] = (signed char)b; T.c[k] = 0; T.t[k] = 1; ++k;
        }
    for (int a = 0; a < 16; ++a)
        for (int b = a + 1; b < 16; ++b)
            for (int c = b + 1; c < 16; ++c) {
                T.a[k] = (signed char)a; T.b[k] = (signed char)b;
                T.c[k] = (signed char)c; T.t[k] = 2; ++k;
            }
    return T;
}
constexpr Tabs TT = make_tabs();

// COL is a template parameter -> all xr[] indices are compile-time constants
// -> xr stays in VGPRs (never scratch). Pair sums CSE across triples.
template<int COL>
__device__ __forceinline__ float elem(const float* __restrict__ xr) {
    constexpr int A = TT.a[COL], B = TT.b[COL], C = TT.c[COL], TY = TT.t[COL];
    if constexpr (TY == 0)      return xr[A];
    else if constexpr (TY == 1) return fmaxf(xr[A] + xr[B] - 1.0f, 0.0f);
    else                        return fmaxf((xr[A] + xr[B]) + xr[C] - 2.0f, 0.0f);
}

// Compute quads J=0..NQ-1 of group G (cols 32G..32G+4*NQ) and stage into the
// wave's slab at [quad][row(=lane)]: granule = J*64 + lane -> lane-contiguous
// ds_write_b128, conflict-free.
template<int G, int J, int NQ>
__device__ __forceinline__ void compute_quads(const float* __restrict__ xr,
                                              v4f* __restrict__ slab, int lane) {
    if constexpr (J < NQ) {
        constexpr int col0 = 32 * G + 4 * J;
        v4f o;
        o.x = elem<col0 + 0>(xr);
        o.y = elem<col0 + 1>(xr);
        o.z = elem<col0 + 2>(xr);
        o.w = elem<col0 + 3>(xr);
        slab[J * 64 + lane] = o;
        compute_quads<G, J + 1, NQ>(xr, slab, lane);
    }
}

template<int G>
__device__ __forceinline__ void do_group(const float* __restrict__ xr,
                                         v4f* __restrict__ slab, int lane,
                                         v4f* __restrict__ blk4, int voffq) {
    constexpr int NQ = (G < 21) ? 8 : 6;   // 174 = 21*8 + 6
    compute_quads<G, 0, NQ>(xr, slab, lane);
    // Drain transposed: store instr m covers rows 8m..8m+7, quads 8G..8G+NQ.
    // Lane l -> (row' = 8m + l/8, quad = 8G + l%8): 8 full 128B chunks/instr.
    // Slab read granule = (l%8)*64 + 8m + l/8: 8 lanes per 4-bank slot with
    // distinct addresses over 4 clocks = 2/clock, conflict-free (m136).
    #pragma unroll
    for (int m = 0; m < 8; ++m) {
        const v4f o = slab[(lane & 7) * 64 + m * 8 + (lane >> 3)];
        if (NQ == 8 || (lane & 7) < NQ)
            blk4[voffq + m * (8 * NC4) + G * 8] = o;
    }
    if constexpr (G + 1 < NG) do_group<G + 1>(xr, slab, lane, blk4, voffq);
}

__global__ __launch_bounds__(256) void luk_kernel(const float* __restrict__ x,
                                                  float* __restrict__ out,
                                                  int nrows) {
    __shared__ v4f slab[4][8 * 64];        // 8 KB per wave, waves independent
    const int t = threadIdx.x;
    const int w = t >> 6, lane = t & 63;
    const int row0 = blockIdx.x * 256 + w * 64;  // this wave's 64 rows
    const int row  = row0 + lane;

    float xr[16];                           // row's x in registers
    const v4f* __restrict__ xv = reinterpret_cast<const v4f*>(x) + (size_t)row * 4;
    *reinterpret_cast<v4f*>(&xr[0])  = xv[0];
    *reinterpret_cast<v4f*>(&xr[4])  = xv[1];
    *reinterpret_cast<v4f*>(&xr[8])  = xv[2];
    *reinterpret_cast<v4f*>(&xr[12]) = xv[3];

    v4f* __restrict__ blk4 = reinterpret_cast<v4f*>(out) + (size_t)row0 * NC4;
    const int voffq = (lane >> 3) * NC4 + (lane & 7);
    do_group<0>(xr, slab[w], lane, blk4, voffq);
}

extern "C" void kernel_launch(void* const* d_in, const int* in_sizes, int n_in,
                              void* d_out, int out_size, void* d_ws, size_t ws_size,
                              hipStream_t stream) {
    const float* x = (const float*)d_in[0];
    float* out = (float*)d_out;
    const int nrows  = in_sizes[0] / 16;     // 131072
    const int blocks = nrows / 256;          // 512 = exactly 2 blocks/CU
    luk_kernel<<<blocks, 256, 0, stream>>>(x, out, nrows);
}

// Round 5
// 368.155 us; speedup vs baseline: 1.2167x; 1.2167x over previous
//
#include <hip/hip_runtime.h>

// Lukasiewicz t-norm feature expansion.
//   out[:, 0:16]    = x
//   out[:, 16:136]  = max(x[a]+x[b] - 1, 0)          (a,b)   lex combos of 16
//   out[:, 136:696] = max((x[a]+x[b]) + x[c] - 2, 0) (a,b,c) lex combos of 16
//
// R7: R5's exact shell (2048 blocks x 256, grid-stride tiles, linear aligned
// dwordx4 stores i = t+256k) with the inner compute stripped to the bone:
//  - per-thread descriptors HOISTED out of the tile loop (thread t's 11 quad
//    slots repeat every tile): each element pre-resolved to two final LDS
//    byte addresses packed in one u32 -> hot loop has NO decode, NO addr VALU.
//  - LDS row = [16 x | 120 raw pairsum | 120 (pairsum-1) | zero@256], so
//    singles/pairs are max(v1+v2+nb,0) with v2=zero broadcast, nb=0;
//    triples max((ps+xc)-2,0) with nb=-2. Bit-exact orders preserved:
//    pairs (xa+xb)-1 computed in pre-phase; triples ((xa+xb)+xc)-2.
//  - hot loop/quad: 8 ds_read_b32 + ~20 VALU + 1 store (R5: 12 ds_read +
//    ~55 VALU + table load).
// Discriminator: if kernel drops ~137 -> ~80 us, LDS/VALU overlap was the
// limiter; if unchanged, write path caps at ~2.7 TB/s (RFO) -> roofline.

#define NCOLS 696
#define NC4   174
#define RPT   16
#define RSTR  260            // floats/row: 16 x | 120 ps | 120 pm1 | zero@256
#define ZOFF  256
#define NQ    (RPT * NC4)    // 2784 quads per tile
#define KITER 11             // ceil(2784/256); last iter: t < 224

typedef float v4f __attribute__((ext_vector_type(4)));

// Per-column descriptor: low16 = slot1 byte offset, high16 = slot2 byte
// offset (within a row; r*1040 added to both at hoist time).
struct DTab { unsigned int v[NCOLS]; };
constexpr DTab make_dtab() {
    DTab d{};
    int pidx[16][16] = {};
    int pi = 0;
    for (int a = 0; a < 16; ++a)
        for (int b = a + 1; b < 16; ++b) pidx[a][b] = pi++;
    int k = 0;
    for (int a = 0; a < 16; ++a)                       // singles: x + 0
        d.v[k++] = (unsigned)(a * 4) | ((unsigned)(ZOFF * 4) << 16);
    for (int a = 0; a < 16; ++a)                       // pairs: (ps-1) + 0
        for (int b = a + 1; b < 16; ++b)
            d.v[k++] = (unsigned)((136 + pidx[a][b]) * 4) | ((unsigned)(ZOFF * 4) << 16);
    for (int a = 0; a < 16; ++a)                       // triples: ps + xc
        for (int b = a + 1; b < 16; ++b)
            for (int c = b + 1; c < 16; ++c)
                d.v[k++] = (unsigned)((16 + pidx[a][b]) * 4) | ((unsigned)(c * 4) << 16);
    return d;
}
__constant__ DTab g_dtab = make_dtab();

// pre-phase pair table: a*4 | (b*4)<<8
struct PTab { unsigned short v[120]; };
constexpr PTab make_ptab() {
    PTab p{};
    int k = 0;
    for (int a = 0; a < 16; ++a)
        for (int b = a + 1; b < 16; ++b)
            p.v[k++] = (unsigned short)((a * 4) | ((b * 4) << 8));
    return p;
}
__constant__ PTab g_ptab = make_ptab();

__device__ __forceinline__ float ldsf(const char* Lb, unsigned off) {
    return *reinterpret_cast<const float*>(Lb + off);
}

__global__ __launch_bounds__(256) void luk_kernel(const float* __restrict__ x,
                                                  float* __restrict__ out,
                                                  int ntiles) {
    __shared__ float L[RPT * RSTR];           // 16.6 KB
    const int t = threadIdx.x;

    // ---- hoisted per-thread element descriptors (identical for all tiles) --
    unsigned pk[KITER][4];                    // packed final LDS byte addrs
    float    nb[KITER];                       // 0.0f (single/pair) or -2.0f
    #pragma unroll
    for (int k = 0; k < KITER; ++k) {
        const int i = t + 256 * k;
        if (i < NQ) {
            const unsigned r  = (unsigned)i / (unsigned)NC4;
            const int      c4 = i - (int)r * NC4;
            const unsigned radd = (r * (unsigned)(RSTR * 4)) * 0x10001u; // both halves; no carry (max 16636)
            const uint4 dv = reinterpret_cast<const uint4*>(g_dtab.v)[c4];
            pk[k][0] = dv.x + radd;
            pk[k][1] = dv.y + radd;
            pk[k][2] = dv.z + radd;
            pk[k][3] = dv.w + radd;
            nb[k] = (c4 < 34) ? 0.0f : -2.0f; // quads are region-homogeneous
        } else {
            pk[k][0] = pk[k][1] = pk[k][2] = pk[k][3] = 0;
            nb[k] = 0.0f;
        }
    }

    const char* __restrict__ Lb = reinterpret_cast<const char*>(L);

    for (int tile = blockIdx.x; tile < ntiles; tile += gridDim.x) {
        const int row0 = tile * RPT;

        {   // stage x: 256 consecutive floats, coalesced; init zero slots
            const int r = t >> 4, a = t & 15;
            L[r * RSTR + a] = x[(size_t)row0 * 16 + t];
            if (t < RPT) L[t * RSTR + ZOFF] = 0.0f;
        }
        __syncthreads();

        // pre-phase: 16 rows x 120 pair sums; write raw ps and ps-1.
        #pragma unroll
        for (int m = 0; m < 8; ++m) {
            const int j = t + 256 * m;
            if (m < 7 || j < RPT * 120) {     // 1920 = 7.5*256
                const unsigned r = (unsigned)j / 120u;
                const int      p = j - (int)r * 120;
                const unsigned pv = g_ptab.v[p];
                const char* xr = reinterpret_cast<const char*>(&L[r * RSTR]);
                const float ps = ldsf(xr, pv & 255u) + ldsf(xr, pv >> 8);
                L[r * RSTR + 16 + p]  = ps;
                L[r * RSTR + 136 + p] = ps - 1.0f;
            }
        }
        __syncthreads();

        // hot loop: 8 pre-resolved ds_read + 3 VALU/elem + linear store.
        v4f* __restrict__ o4 = reinterpret_cast<v4f*>(out + (size_t)row0 * NCOLS);
        #pragma unroll
        for (int k = 0; k < KITER; ++k) {
            if (k < KITER - 1 || t < NQ - 256 * (KITER - 1)) {
                const float nbk = nb[k];
                v4f o;
                { const unsigned p0 = pk[k][0];
                  o.x = fmaxf((ldsf(Lb, p0 & 0xffffu) + ldsf(Lb, p0 >> 16)) + nbk, 0.0f); }
                { const unsigned p1 = pk[k][1];
                  o.y = fmaxf((ldsf(Lb, p1 & 0xffffu) + ldsf(Lb, p1 >> 16)) + nbk, 0.0f); }
                { const unsigned p2 = pk[k][2];
                  o.z = fmaxf((ldsf(Lb, p2 & 0xffffu) + ldsf(Lb, p2 >> 16)) + nbk, 0.0f); }
                { const unsigned p3 = pk[k][3];
                  o.w = fmaxf((ldsf(Lb, p3 & 0xffffu) + ldsf(Lb, p3 >> 16)) + nbk, 0.0f); }
                o4[t + 256 * k] = o;
            }
        }
        __syncthreads();   // L reused next tile
    }
}

extern "C" void kernel_launch(void* const* d_in, const int* in_sizes, int n_in,
                              void* d_out, int out_size, void* d_ws, size_t ws_size,
                              hipStream_t stream) {
    const float* x = (const float*)d_in[0];
    float* out = (float*)d_out;
    const int nrows  = in_sizes[0] / 16;            // 131072
    const int ntiles = nrows / RPT;                 // 8192 (nrows % 16 == 0)
    const int blocks = ntiles < 2048 ? ntiles : 2048;
    luk_kernel<<<blocks, 256, 0, stream>>>(x, out, ntiles);
}

// Round 6
// 364.786 us; speedup vs baseline: 1.2279x; 1.0092x over previous
//
#include <hip/hip_runtime.h>

// Lukasiewicz t-norm feature expansion.
//   out[:, 0:16]    = x
//   out[:, 16:136]  = max(x[a]+x[b] - 1, 0)        (a,b)   lex combos of 16
//   out[:, 136:696] = max(x[a]+x[b]+x[c] - 2, 0)   (a,b,c) lex combos of 16
//
// R8: ZERO-BARRIER design. Evidence: R2/R5/R7 all land at kernel ~130 us =
// serial sum of (LDS ~50 + VALU ~18 + store drain ~57) despite wildly
// different per-quad op counts -> pipes don't overlap. Cause (per m97 asm
// analysis): __syncthreads compiles to s_waitcnt vmcnt(0) before s_barrier,
// so each tile all waves stall until ALL their global stores retire through
// the backpressured write path before touching LDS for the next tile.
// Fix: one wave = one 16-row tile, LDS slab is WAVE-PRIVATE -> no barrier
// anywhere, stores are never awaited (free-flow like the 6.4 TB/s fill).
// Staging needs only intra-wave lgkmcnt ordering (compiler-inserted).
// FP order identical to R2 (absmax 0 there): ((xa+xb)+xc) - float(bias).

#define NCOLS 696
#define NC4   174          // quads per row
#define RPT   16           // rows per wave-tile
#define RSTR  20           // slab row stride (floats): 16 x | zero@16 | pad -> 80B, b128-aligned

typedef float v4f __attribute__((ext_vector_type(4)));

struct ColTab { unsigned int v[NCOLS]; };

// Packed per-column descriptor: a[4:0] | b[9:5] | c[14:10] | bias[16:15]
// index 16 -> zero slot. Order matches itertools.combinations (lex).
constexpr ColTab make_tab() {
    ColTab t{};
    int k = 0;
    for (int a = 0; a < 16; ++a)
        t.v[k++] = (unsigned)a | (16u << 5) | (16u << 10);
    for (int a = 0; a < 16; ++a)
        for (int b = a + 1; b < 16; ++b)
            t.v[k++] = (unsigned)a | ((unsigned)b << 5) | (16u << 10) | (1u << 15);
    for (int a = 0; a < 16; ++a)
        for (int b = a + 1; b < 16; ++b)
            for (int c = b + 1; c < 16; ++c)
                t.v[k++] = (unsigned)a | ((unsigned)b << 5) | ((unsigned)c << 10) | (2u << 15);
    return t;
}

__constant__ ColTab g_tab = make_tab();

__device__ __forceinline__ float tnorm(const float* __restrict__ xr, unsigned v) {
    return fmaxf(xr[v & 31u] + xr[(v >> 5) & 31u] + xr[(v >> 10) & 31u]
                 - (float)((v >> 15) & 3u), 0.0f);
}

__global__ __launch_bounds__(256) void luk_kernel(const float* __restrict__ x,
                                                  float* __restrict__ out,
                                                  int nrows, int ntiles) {
    // 4 independent per-wave slabs; no __syncthreads in this kernel.
    __shared__ float slabs[4][RPT * RSTR];
    const int t = threadIdx.x;
    const int w = t >> 6, lane = t & 63;
    const int tile = blockIdx.x * 4 + w;      // one tile per wave, exactly
    if (tile >= ntiles) return;               // whole-wave exit; no barriers exist

    float* __restrict__ slab = slabs[w];
    const int row0 = tile * RPT;
    const int rlim = min(RPT, nrows - row0);

    {   // stage: 64 lanes x dwordx4 = this wave's 16 rows x 16 floats (1 KB,
        // fully coalesced). Slab row stride 80B keeps writes b128-aligned.
        const int r  = lane >> 2;
        const int c0 = (lane & 3) * 4;
        v4f v = {0.0f, 0.0f, 0.0f, 0.0f};
        if (r < rlim)
            v = *reinterpret_cast<const v4f*>(x + (size_t)(row0 + r) * 16 + c0);
        *reinterpret_cast<v4f*>(&slab[r * RSTR + c0]) = v;
        if (lane < RPT) slab[lane * RSTR + 16] = 0.0f;   // zero slot
    }
    // wave-private RAW through LDS: compiler inserts s_waitcnt lgkmcnt; no
    // cross-wave visibility needed, so no s_barrier and NO vmcnt(0) drain.

    const uint4* __restrict__ tab4 = reinterpret_cast<const uint4*>(g_tab.v);
    v4f* __restrict__ o4 = reinterpret_cast<v4f*>(out) + (size_t)tile * (RPT * NC4);
    const int nq = rlim * NC4;                // 2784 for full tiles

    // 44 iterations; each wave-store = 64 lanes x 16B = 1024B contiguous,
    // 128B-line-aligned (tile base = tile*44544B). Stores are never waited
    // on: they drain while the LDS pipe works on subsequent iterations.
    #pragma unroll 4
    for (int j = 0; j < (RPT * NC4 + 63) / 64; ++j) {
        const int q = j * 64 + lane;
        if (q < nq) {
            const unsigned r  = (unsigned)q / (unsigned)NC4;
            const int      c4 = q - (int)r * NC4;
            const uint4 tv = tab4[c4];
            const float* __restrict__ xr = &slab[r * RSTR];
            v4f o;
            o.x = tnorm(xr, tv.x);
            o.y = tnorm(xr, tv.y);
            o.z = tnorm(xr, tv.z);
            o.w = tnorm(xr, tv.w);
            o4[q] = o;
        }
    }
}

extern "C" void kernel_launch(void* const* d_in, const int* in_sizes, int n_in,
                              void* d_out, int out_size, void* d_ws, size_t ws_size,
                              hipStream_t stream) {
    const float* x = (const float*)d_in[0];
    float* out = (float*)d_out;
    const int nrows  = in_sizes[0] / 16;          // 131072
    const int ntiles = (nrows + RPT - 1) / RPT;   // 8192
    const int blocks = (ntiles + 3) / 4;          // 2048: 8 blocks/CU, 32 waves/CU
    luk_kernel<<<blocks, 256, 0, stream>>>(x, out, nrows, ntiles);
}